// Round 2
// baseline (475.993 us; speedup 1.0000x reference)
//
#include <hip/hip_runtime.h>

using half8   = __attribute__((ext_vector_type(8))) _Float16;
using floatx4 = __attribute__((ext_vector_type(4))) float;

// Repack quant_weights [co][c][kh][kw] fp32{-1,0,1} -> wre[(kh*3+kw)][co][c] f16
__global__ void repack_weights(const float* __restrict__ qw,
                               _Float16* __restrict__ wre, int n) {
  int t = blockIdx.x * 256 + threadIdx.x;
  if (t >= n) return;
  int c  = t & 255;
  int co = (t >> 8) & 255;
  int s  = t >> 16;                      // 0..8 = kh*3+kw
  wre[t] = (_Float16)qw[(co * 256 + c) * 9 + s];
}

// Implicit-GEMM binary conv: out[b,co,h,w] = scale[co]*sum sign*x + bias[co]
// Block tile: 256 cout x 112 pixels (2 rows x 56); each wave owns a 64-cout
// quarter (m=4 MFMA tiles) so one B-fragment ds_read feeds 4 MFMAs.
// K-chunks of 32 input channels.
// LDS x-tile: xs[row 0..3][col 0..57][c 0..31] f16 (c innermost -> ds_read_b128,
// wave's 64 lanes read a contiguous 1 KiB -> conflict-free)
__global__ __launch_bounds__(256, 3) void binconv_mfma(
    const float* __restrict__ x,
    const float* __restrict__ scale,
    const float* __restrict__ bias,
    const _Float16* __restrict__ wre,
    float* __restrict__ out)
{
  __shared__ _Float16 xs[4 * 58 * 32];   // 14,848 B

  const int tid  = threadIdx.x;
  const int nb   = blockIdx.x;           // 0..895 : (b, h-pair)
  const int b    = nb / 28;
  const int h0   = (nb % 28) * 2;
  const int wave = tid >> 6;
  const int lane = tid & 63;
  const int nl   = lane & 15;            // MFMA: n (B) / m (A) index
  const int quad = lane >> 4;            // MFMA: k-group
  const int co_wave = wave * 64;         // each wave: 64 couts (4 m-tiles)

  // zero halo columns (col 0 and 57) once; never overwritten afterwards
  {
    int c = tid & 31;
    int g = tid >> 5;                    // 0..7
    int r = g >> 1;
    int side = g & 1;
    xs[(r * 58 + side * 57) * 32 + c] = (_Float16)0.0f;
  }

  // per-lane B-fragment base byte offsets within xs for j = 0..6
  int bbase[7];
#pragma unroll
  for (int j = 0; j < 7; ++j) {
    int n = j * 16 + nl;                 // 0..111 pixel within tile
    int r = (n >= 56) ? 1 : 0;
    int w = n - r * 56;
    bbase[j] = (r * 58 + w) * 64 + quad * 16;   // bytes; (+ (kh*58+kw)*64 per shift)
  }

  // per-lane A-fragment pointers (one per 16-row m-tile)
  const _Float16* aptr[4];
#pragma unroll
  for (int mi = 0; mi < 4; ++mi)
    aptr[mi] = wre + (co_wave + mi * 16 + nl) * 256 + quad * 8;

  floatx4 acc[4][7];
#pragma unroll
  for (int mi = 0; mi < 4; ++mi)
#pragma unroll
    for (int j = 0; j < 7; ++j)
      acc[mi][j] = (floatx4){0.f, 0.f, 0.f, 0.f};

  const int sc = tid & 31;               // staging: channel within chunk
  const int sg = tid >> 5;               // staging: work-group 0..7

  for (int c0 = 0; c0 < 256; c0 += 32) {
    // ---- stage x chunk into LDS: 32c x 4 rows x 56 cols (+pad), fp32->f16 ----
    for (int p = sg; p < 28; p += 8) {   // p = r*7 + wg
      int r  = p / 7;
      int wg = p - r * 7;
      int h  = h0 - 1 + r;
      int w0 = wg * 8;
      float v[8];
      if (h >= 0 && h < 56) {
        const float* src = x + (((long)b * 256 + c0 + sc) * 56 + h) * 56 + w0;
        float4 u0 = *reinterpret_cast<const float4*>(src);
        float4 u1 = *reinterpret_cast<const float4*>(src + 4);
        v[0] = u0.x; v[1] = u0.y; v[2] = u0.z; v[3] = u0.w;
        v[4] = u1.x; v[5] = u1.y; v[6] = u1.z; v[7] = u1.w;
      } else {
#pragma unroll
        for (int i = 0; i < 8; ++i) v[i] = 0.f;
      }
      int basei = (r * 58 + 1 + w0) * 32 + sc;
#pragma unroll
      for (int i = 0; i < 8; ++i) xs[basei + i * 32] = (_Float16)v[i];
    }
    __syncthreads();

    // ---- compute: 9 shifts x (4m x 7n) MFMA 16x16x32 f16, K = this c-chunk ----
#pragma unroll
    for (int s = 0; s < 9; ++s) {
      const int kh = s / 3, kw = s - kh * 3;
      half8 a[4];
#pragma unroll
      for (int mi = 0; mi < 4; ++mi)
        a[mi] = *reinterpret_cast<const half8*>(aptr[mi] + s * 65536 + c0);
      const int soff = (kh * 58 + kw) * 64;
#pragma unroll
      for (int j = 0; j < 7; ++j) {
        half8 bf = *reinterpret_cast<const half8*>(
            reinterpret_cast<const char*>(xs) + bbase[j] + soff);
#pragma unroll
        for (int mi = 0; mi < 4; ++mi)
          acc[mi][j] = __builtin_amdgcn_mfma_f32_16x16x32_f16(a[mi], bf, acc[mi][j], 0, 0, 0);
      }
    }
    __syncthreads();
  }

  // ---- epilogue: scale + bias, fp32 stores ----
  // C/D layout: n = lane&15 (col), m = quad*4 + reg (row)
#pragma unroll
  for (int mi = 0; mi < 4; ++mi) {
#pragma unroll
    for (int reg = 0; reg < 4; ++reg) {
      int co = co_wave + mi * 16 + quad * 4 + reg;
      float s_ = scale[co];
      float bi = bias[co];
#pragma unroll
      for (int j = 0; j < 7; ++j) {
        int n = j * 16 + nl;
        int r = (n >= 56) ? 1 : 0;
        int w = n - r * 56;
        out[(((long)b * 256 + co) * 56 + (h0 + r)) * 56 + w] =
            acc[mi][j][reg] * s_ + bi;
      }
    }
  }
}

extern "C" void kernel_launch(void* const* d_in, const int* in_sizes, int n_in,
                              void* d_out, int out_size, void* d_ws, size_t ws_size,
                              hipStream_t stream) {
  const float* x     = (const float*)d_in[0];   // [32,256,56,56]
  const float* scale = (const float*)d_in[1];   // [256]
  const float* qw    = (const float*)d_in[2];   // [256,256,3,3] in {-1,0,1}
  const float* bias  = (const float*)d_in[3];   // [256]
  float* out = (float*)d_out;                   // [32,256,56,56] fp32

  _Float16* wre = (_Float16*)d_ws;              // 9*256*256 f16 = 1.13 MB scratch

  const int nw = 9 * 256 * 256;
  repack_weights<<<(nw + 255) / 256, 256, 0, stream>>>(qw, wre, nw);

  dim3 grid(896);                               // (b, h-pair); block = 256 cout
  binconv_mfma<<<grid, 256, 0, stream>>>(x, scale, bias, wre, out);
}

// Round 3
// 373.078 us; speedup vs baseline: 1.2759x; 1.2759x over previous
//
#include <hip/hip_runtime.h>

using half8   = __attribute__((ext_vector_type(8))) _Float16;
using floatx4 = __attribute__((ext_vector_type(4))) float;

// Repack quant_weights [co][c][kh][kw] fp32{-1,0,1} -> wre[(kh*3+kw)][co][c] f16
__global__ void repack_weights(const float* __restrict__ qw,
                               _Float16* __restrict__ wre, int n) {
  int t = blockIdx.x * 256 + threadIdx.x;
  if (t >= n) return;
  int c  = t & 255;
  int co = (t >> 8) & 255;
  int s  = t >> 16;                      // 0..8 = kh*3+kw
  wre[t] = (_Float16)qw[(co * 256 + c) * 9 + s];
}

// Implicit-GEMM binary conv: out[b,co,h,w] = scale[co]*sum sign*x + bias[co]
// Block tile: 256 cout x 112 pixels (2 rows x 56); each wave owns a 64-cout
// quarter (m=4 MFMA tiles) so one B-fragment ds_read feeds 4 MFMAs.
// __launch_bounds__(256,2): 256-reg/wave budget -> acc[4][7] (112) + A-frags
// fit WITHOUT spilling (R2's (256,3) cap at ~170 spilled: +64MB WRITE_SIZE).
// LDS x-tile: xs[row 0..3][col 0..57][c 0..31] f16. Each 64B block = one
// (row,col) position; block bank-half = position parity. Staging stores are
// rotated by (i+sg)&7 so the two wave-halves always hit opposite halves.
__global__ __launch_bounds__(256, 2) void binconv_mfma(
    const float* __restrict__ x,
    const float* __restrict__ scale,
    const float* __restrict__ bias,
    const _Float16* __restrict__ wre,
    float* __restrict__ out)
{
  __shared__ _Float16 xs[4 * 58 * 32];   // 14,848 B

  const int tid  = threadIdx.x;
  const int nb   = blockIdx.x;           // 0..895 : (b, h-pair)
  const int b    = nb / 28;
  const int h0   = (nb % 28) * 2;
  const int wave = tid >> 6;
  const int lane = tid & 63;
  const int nl   = lane & 15;            // MFMA: n (B) / m (A) index
  const int quad = lane >> 4;            // MFMA: k-group
  const int co_wave = wave * 64;         // each wave: 64 couts (4 m-tiles)

  // zero halo columns (col 0 and 57) once; never overwritten afterwards
  {
    int c = tid & 31;
    int g = tid >> 5;                    // 0..7
    int r = g >> 1;
    int side = g & 1;
    xs[(r * 58 + side * 57) * 32 + c] = (_Float16)0.0f;
  }

  // per-lane B-fragment base byte offsets within xs for j = 0..6
  int bbase[7];
#pragma unroll
  for (int j = 0; j < 7; ++j) {
    int n = j * 16 + nl;                 // 0..111 pixel within tile
    int r = (n >= 56) ? 1 : 0;
    int w = n - r * 56;
    bbase[j] = (r * 58 + w) * 64 + quad * 16;   // bytes; (+ (kh*58+kw)*64 per shift)
  }

  // per-lane A-fragment pointers (one per 16-row m-tile)
  const _Float16* aptr[4];
#pragma unroll
  for (int mi = 0; mi < 4; ++mi)
    aptr[mi] = wre + (co_wave + mi * 16 + nl) * 256 + quad * 8;

  floatx4 acc[4][7];
#pragma unroll
  for (int mi = 0; mi < 4; ++mi)
#pragma unroll
    for (int j = 0; j < 7; ++j)
      acc[mi][j] = (floatx4){0.f, 0.f, 0.f, 0.f};

  const int sc = tid & 31;               // staging: channel within chunk
  const int sg = tid >> 5;               // staging: work-group 0..7

  for (int c0 = 0; c0 < 256; c0 += 32) {
    // ---- stage x chunk into LDS: 32c x 4 rows x 56 cols (+pad), fp32->f16 ----
    for (int p = sg; p < 28; p += 8) {   // p = r*7 + wg
      int r  = p / 7;
      int wg = p - r * 7;
      int h  = h0 - 1 + r;
      int w0 = wg * 8;
      float v[8];
      if (h >= 0 && h < 56) {
        const float* src = x + (((long)b * 256 + c0 + sc) * 56 + h) * 56 + w0;
        float4 u0 = *reinterpret_cast<const float4*>(src);
        float4 u1 = *reinterpret_cast<const float4*>(src + 4);
        v[0] = u0.x; v[1] = u0.y; v[2] = u0.z; v[3] = u0.w;
        v[4] = u1.x; v[5] = u1.y; v[6] = u1.z; v[7] = u1.w;
      } else {
#pragma unroll
        for (int i = 0; i < 8; ++i) v[i] = 0.f;
      }
      int basei = (r * 58 + 1 + w0) * 32 + sc;
      // store-order rotation: wave-halves (sg even/odd) write positions with
      // col-offset differing by an ODD amount -> opposite bank halves -> no
      // bank conflict (was 4-way: stride-8 positions share a bank half).
#pragma unroll
      for (int i = 0; i < 8; ++i) {
        int j = (i + sg) & 7;
        xs[basei + j * 32] = (_Float16)v[j];
      }
    }
    __syncthreads();

    // ---- compute: 9 shifts x (4m x 7n) MFMA 16x16x32 f16, K = this c-chunk ----
#pragma unroll
    for (int s = 0; s < 9; ++s) {
      const int kh = s / 3, kw = s - kh * 3;
      half8 a[4];
#pragma unroll
      for (int mi = 0; mi < 4; ++mi)
        a[mi] = *reinterpret_cast<const half8*>(aptr[mi] + s * 65536 + c0);
      const int soff = (kh * 58 + kw) * 64;
#pragma unroll
      for (int j = 0; j < 7; ++j) {
        half8 bf = *reinterpret_cast<const half8*>(
            reinterpret_cast<const char*>(xs) + bbase[j] + soff);
#pragma unroll
        for (int mi = 0; mi < 4; ++mi)
          acc[mi][j] = __builtin_amdgcn_mfma_f32_16x16x32_f16(a[mi], bf, acc[mi][j], 0, 0, 0);
      }
    }
    __syncthreads();
  }

  // ---- epilogue: scale + bias, fp32 stores ----
  // C/D layout: n = lane&15 (col), m = quad*4 + reg (row)
#pragma unroll
  for (int mi = 0; mi < 4; ++mi) {
#pragma unroll
    for (int reg = 0; reg < 4; ++reg) {
      int co = co_wave + mi * 16 + quad * 4 + reg;
      float s_ = scale[co];
      float bi = bias[co];
#pragma unroll
      for (int j = 0; j < 7; ++j) {
        int n = j * 16 + nl;
        int r = (n >= 56) ? 1 : 0;
        int w = n - r * 56;
        out[(((long)b * 256 + co) * 56 + (h0 + r)) * 56 + w] =
            acc[mi][j][reg] * s_ + bi;
      }
    }
  }
}

extern "C" void kernel_launch(void* const* d_in, const int* in_sizes, int n_in,
                              void* d_out, int out_size, void* d_ws, size_t ws_size,
                              hipStream_t stream) {
  const float* x     = (const float*)d_in[0];   // [32,256,56,56]
  const float* scale = (const float*)d_in[1];   // [256]
  const float* qw    = (const float*)d_in[2];   // [256,256,3,3] in {-1,0,1}
  const float* bias  = (const float*)d_in[3];   // [256]
  float* out = (float*)d_out;                   // [32,256,56,56] fp32

  _Float16* wre = (_Float16*)d_ws;              // 9*256*256 f16 = 1.13 MB scratch

  const int nw = 9 * 256 * 256;
  repack_weights<<<(nw + 255) / 256, 256, 0, stream>>>(qw, wre, nw);

  dim3 grid(896);                               // (b, h-pair); block = 256 cout
  binconv_mfma<<<grid, 256, 0, stream>>>(x, scale, bias, wre, out);
}

// Round 4
// 332.249 us; speedup vs baseline: 1.4326x; 1.1229x over previous
//
#include <hip/hip_runtime.h>

using half8   = __attribute__((ext_vector_type(8))) _Float16;
using floatx4 = __attribute__((ext_vector_type(4))) float;
using short8  = __attribute__((ext_vector_type(8))) short;

// xt layout: [b 32][cchunk 8][hh 58][ww 64][slot 40] f16  (80 B per position,
// slots 32..39 zero pad -> read bank-quad (5*pos+quad)%8 is a permutation).
// hh = h+1 (rows 0,57 zero), ww = w+1 (cols 0,57..63 zero).
#define XT_ROW_ELEMS 2560                       // 64*40
#define XT_ROW_BYTES 5120
#define XT_OFF ((size_t)2 << 20)                // wre in [0, 1.18MB); xt at +2MB
#define XT_BYTES ((size_t)256 * 58 * XT_ROW_BYTES)   // 76,021,760

__device__ __forceinline__ void dma16(const void* g, void* l) {
  __builtin_amdgcn_global_load_lds(
      (const __attribute__((address_space(1))) void*)g,
      (__attribute__((address_space(3))) void*)l, 16, 0, 0);
}

// ---- prep: fused weight repack + x transpose/convert/pad ----
// blocks [0,14848): transpose one (b,cc,hh) row; blocks [14848,17152): repack
__global__ __launch_bounds__(256) void prep_kernel(
    const float* __restrict__ x, const float* __restrict__ qw,
    _Float16* __restrict__ wre, _Float16* __restrict__ xt)
{
  const int bid = blockIdx.x;
  const int t = threadIdx.x;
  if (bid >= 14848) {                           // ---- weight repack ----
    int idx = (bid - 14848) * 256 + t;          // < 9*256*256
    int c = idx & 255, co = (idx >> 8) & 255, s = idx >> 16;
    wre[idx] = (_Float16)qw[(co * 256 + c) * 9 + s];
    return;
  }
  // ---- transpose one padded row ----
  __shared__ _Float16 lt[32 * 57];              // [c32][w56 +1 pad]
  const int hh = bid % 58;
  const int bc = bid / 58;                      // b*8 + cc
  const int cc = bc & 7, b = bc >> 3;
  _Float16* dst = xt + ((size_t)bc * 58 + hh) * XT_ROW_ELEMS;
  const bool interior = (hh >= 1) && (hh <= 56);
  if (interior) {
    const int c = t >> 3, j = t & 7;            // 8 threads cover 56 w
    const float* src = x + (((size_t)(b * 256 + cc * 32 + c)) * 56 + (hh - 1)) * 56 + j * 7;
#pragma unroll
    for (int i = 0; i < 7; ++i) lt[c * 57 + j * 7 + i] = (_Float16)src[i];
  }
  __syncthreads();
  // write 320 16B-chunks (64 pos x 5 slots-of-8) coalesced
  for (int ch = t; ch < 320; ch += 256) {
    int pos = ch / 5, sl = ch - pos * 5;
    short8 v = {0, 0, 0, 0, 0, 0, 0, 0};
    if (interior && sl < 4 && pos >= 1 && pos <= 56) {
      int w = pos - 1;
#pragma unroll
      for (int i = 0; i < 8; ++i)
        v[i] = __builtin_bit_cast(short, lt[(sl * 8 + i) * 57 + w]);
    }
    *reinterpret_cast<short8*>(dst + ch * 8) = v;
  }
}

// ---- main conv: DMA-staged, double-buffered, conflict-free LDS ----
// Block: 256 cout x 112 px (2 rows x 56). Wave: 64 cout (m=4), j=7 n-tiles.
__global__ __launch_bounds__(256, 2) void binconv_mfma(
    const float* __restrict__ scale, const float* __restrict__ bias,
    const _Float16* __restrict__ wre, const _Float16* __restrict__ xt,
    float* __restrict__ out)
{
  __shared__ _Float16 xs[2 * 4 * 64 * 40];      // 2 x 20,480 B

  const int tid  = threadIdx.x;
  const int nb   = blockIdx.x;                  // (b, h-pair)
  const int b    = nb / 28;
  const int h0   = (nb % 28) * 2;
  const int wave = tid >> 6;
  const int lane = tid & 63;
  const int nl   = lane & 15;
  const int quad = lane >> 4;
  const int co_wave = wave * 64;

  int bbase[7];                                 // byte offsets, 80B/pos stride
#pragma unroll
  for (int j = 0; j < 7; ++j) {
    int n = j * 16 + nl;
    int r = (n >= 56) ? 1 : 0;
    int w = n - r * 56;
    bbase[j] = (r * 64 + w) * 80 + quad * 16;
  }

  const _Float16* aptr[4];
#pragma unroll
  for (int mi = 0; mi < 4; ++mi)
    aptr[mi] = wre + (co_wave + mi * 16 + nl) * 256 + quad * 8;

  floatx4 acc[4][7];
#pragma unroll
  for (int mi = 0; mi < 4; ++mi)
#pragma unroll
    for (int j = 0; j < 7; ++j)
      acc[mi][j] = (floatx4){0.f, 0.f, 0.f, 0.f};

  // staging: wave handles padded row hh = h0 + wave (always in-bounds 0..57)
  const char* xsrc = (const char*)(xt + ((size_t)(b * 8) * 58 + h0) * XT_ROW_ELEMS);
  const int wlane = wave * XT_ROW_BYTES + lane * 16;
  const int wldso = wave * XT_ROW_BYTES;

  // prologue: DMA chunk 0 -> buf 0
#pragma unroll
  for (int i = 0; i < 5; ++i)
    dma16(xsrc + wlane + i * 1024, (char*)xs + wldso + i * 1024);

  int bufoff = 0;
  for (int cc = 0; cc < 8; ++cc) {
    __syncthreads();                            // drains this chunk's DMA
    if (cc < 7) {                               // prefetch next chunk
      const char* srcn = xsrc + (size_t)(cc + 1) * (58 * XT_ROW_BYTES);
#pragma unroll
      for (int i = 0; i < 5; ++i)
        dma16(srcn + wlane + i * 1024,
              (char*)xs + (bufoff ^ 20480) + wldso + i * 1024);
    }
    const int c0 = cc * 32;
    const char* xb = (const char*)xs + bufoff;
#pragma unroll
    for (int s = 0; s < 9; ++s) {
      const int kh = s / 3, kw = s - kh * 3;
      half8 a[4];
#pragma unroll
      for (int mi = 0; mi < 4; ++mi)
        a[mi] = *reinterpret_cast<const half8*>(aptr[mi] + s * 65536 + c0);
      const int soff = (kh * 64 + kw) * 80;
#pragma unroll
      for (int j = 0; j < 7; ++j) {
        half8 bf = *reinterpret_cast<const half8*>(xb + bbase[j] + soff);
#pragma unroll
        for (int mi = 0; mi < 4; ++mi)
          acc[mi][j] = __builtin_amdgcn_mfma_f32_16x16x32_f16(a[mi], bf, acc[mi][j], 0, 0, 0);
      }
    }
    bufoff ^= 20480;
  }

  // epilogue: C/D layout n=lane&15, m=quad*4+reg
#pragma unroll
  for (int mi = 0; mi < 4; ++mi) {
#pragma unroll
    for (int reg = 0; reg < 4; ++reg) {
      int co = co_wave + mi * 16 + quad * 4 + reg;
      float s_ = scale[co];
      float bi = bias[co];
#pragma unroll
      for (int j = 0; j < 7; ++j) {
        int n = j * 16 + nl;
        int r = (n >= 56) ? 1 : 0;
        int w = n - r * 56;
        out[(((size_t)b * 256 + co) * 56 + (h0 + r)) * 56 + w] =
            acc[mi][j][reg] * s_ + bi;
      }
    }
  }
}

// ---------------- fallback path (ws too small): R3 kernels ----------------
__global__ void repack_weights(const float* __restrict__ qw,
                               _Float16* __restrict__ wre, int n) {
  int t = blockIdx.x * 256 + threadIdx.x;
  if (t >= n) return;
  int c = t & 255, co = (t >> 8) & 255, s = t >> 16;
  wre[t] = (_Float16)qw[(co * 256 + c) * 9 + s];
}

__global__ __launch_bounds__(256, 2) void binconv_fallback(
    const float* __restrict__ x, const float* __restrict__ scale,
    const float* __restrict__ bias, const _Float16* __restrict__ wre,
    float* __restrict__ out)
{
  __shared__ _Float16 xsl[4 * 58 * 32];
  const int tid = threadIdx.x;
  const int nb = blockIdx.x;
  const int b = nb / 28;
  const int h0 = (nb % 28) * 2;
  const int wave = tid >> 6;
  const int lane = tid & 63;
  const int nl = lane & 15;
  const int quad = lane >> 4;
  const int co_wave = wave * 64;
  {
    int c = tid & 31, g = tid >> 5, r = g >> 1, side = g & 1;
    xsl[(r * 58 + side * 57) * 32 + c] = (_Float16)0.0f;
  }
  int bbase[7];
#pragma unroll
  for (int j = 0; j < 7; ++j) {
    int n = j * 16 + nl;
    int r = (n >= 56) ? 1 : 0;
    int w = n - r * 56;
    bbase[j] = (r * 58 + w) * 64 + quad * 16;
  }
  const _Float16* aptr[4];
#pragma unroll
  for (int mi = 0; mi < 4; ++mi)
    aptr[mi] = wre + (co_wave + mi * 16 + nl) * 256 + quad * 8;
  floatx4 acc[4][7];
#pragma unroll
  for (int mi = 0; mi < 4; ++mi)
#pragma unroll
    for (int j = 0; j < 7; ++j) acc[mi][j] = (floatx4){0.f, 0.f, 0.f, 0.f};
  const int sc = tid & 31, sg = tid >> 5;
  for (int c0 = 0; c0 < 256; c0 += 32) {
    for (int p = sg; p < 28; p += 8) {
      int r = p / 7, wg = p - r * 7, h = h0 - 1 + r, w0 = wg * 8;
      float v[8];
      if (h >= 0 && h < 56) {
        const float* src = x + (((size_t)b * 256 + c0 + sc) * 56 + h) * 56 + w0;
        float4 u0 = *reinterpret_cast<const float4*>(src);
        float4 u1 = *reinterpret_cast<const float4*>(src + 4);
        v[0] = u0.x; v[1] = u0.y; v[2] = u0.z; v[3] = u0.w;
        v[4] = u1.x; v[5] = u1.y; v[6] = u1.z; v[7] = u1.w;
      } else {
#pragma unroll
        for (int i = 0; i < 8; ++i) v[i] = 0.f;
      }
      int basei = (r * 58 + 1 + w0) * 32 + sc;
#pragma unroll
      for (int i = 0; i < 8; ++i) xsl[basei + i * 32] = (_Float16)v[i];
    }
    __syncthreads();
#pragma unroll
    for (int s = 0; s < 9; ++s) {
      const int kh = s / 3, kw = s - kh * 3;
      half8 a[4];
#pragma unroll
      for (int mi = 0; mi < 4; ++mi)
        a[mi] = *reinterpret_cast<const half8*>(aptr[mi] + s * 65536 + c0);
      const int soff = (kh * 58 + kw) * 64;
#pragma unroll
      for (int j = 0; j < 7; ++j) {
        half8 bf = *reinterpret_cast<const half8*>(
            reinterpret_cast<const char*>(xsl) + bbase[j] + soff);
#pragma unroll
        for (int mi = 0; mi < 4; ++mi)
          acc[mi][j] = __builtin_amdgcn_mfma_f32_16x16x32_f16(a[mi], bf, acc[mi][j], 0, 0, 0);
      }
    }
    __syncthreads();
  }
#pragma unroll
  for (int mi = 0; mi < 4; ++mi) {
#pragma unroll
    for (int reg = 0; reg < 4; ++reg) {
      int co = co_wave + mi * 16 + quad * 4 + reg;
      float s_ = scale[co];
      float bi = bias[co];
#pragma unroll
      for (int j = 0; j < 7; ++j) {
        int n = j * 16 + nl;
        int r = (n >= 56) ? 1 : 0;
        int w = n - r * 56;
        out[(((size_t)b * 256 + co) * 56 + (h0 + r)) * 56 + w] =
            acc[mi][j][reg] * s_ + bi;
      }
    }
  }
}

extern "C" void kernel_launch(void* const* d_in, const int* in_sizes, int n_in,
                              void* d_out, int out_size, void* d_ws, size_t ws_size,
                              hipStream_t stream) {
  const float* x     = (const float*)d_in[0];   // [32,256,56,56]
  const float* scale = (const float*)d_in[1];   // [256]
  const float* qw    = (const float*)d_in[2];   // [256,256,3,3] in {-1,0,1}
  const float* bias  = (const float*)d_in[3];   // [256]
  float* out = (float*)d_out;

  _Float16* wre = (_Float16*)d_ws;

  if (ws_size >= XT_OFF + XT_BYTES) {
    _Float16* xt = (_Float16*)((char*)d_ws + XT_OFF);
    prep_kernel<<<17152, 256, 0, stream>>>(x, qw, wre, xt);
    binconv_mfma<<<896, 256, 0, stream>>>(scale, bias, wre, xt, out);
  } else {
    repack_weights<<<2304, 256, 0, stream>>>(qw, wre, 9 * 256 * 256);
    binconv_fallback<<<896, 256, 0, stream>>>(x, scale, bias, wre, out);
  }
}